// Round 6
// baseline (195.355 us; speedup 1.0000x reference)
//
#include <hip/hip_runtime.h>

#define NCH   256
#define NPROT 320
#define HW    16384      // 128*128
#define TAU   20.0f
#define EPSN  1e-4f

typedef _Float16 half8 __attribute__((ext_vector_type(8)));
typedef float    f32x4 __attribute__((ext_vector_type(4)));

// ---------------------------------------------------------------------------
// MEASUREMENT ROUND (R6): kernels are byte-identical to R5 (passed, absmax 0).
// k_main is launched 3x (idempotent: pure function of qry/PTh/PTl, every
// output word rewritten). dur_R6 - dur_R5 = 2 * k_main_warm. This resolves
// the 3x contradiction between bottom-up model (~10us) and subtraction
// (~32.5us) that four blind structural variants could not.
// ---------------------------------------------------------------------------

// ---------------------------------------------------------------------------
// Kernel 1a: avg-pool sup_x (5,256,128,128) over 16x16 cells -> praw[p][c]
// ---------------------------------------------------------------------------
__global__ __launch_bounds__(256) void k_pool(const float* __restrict__ sup_x,
                                              float* __restrict__ praw) {
    int b = blockIdx.x;            // s*256 + c
    int t = threadIdx.x;
    const float4* plane = (const float4*)(sup_x + (size_t)b * HW);
    float rsum[8];
    #pragma unroll
    for (int r = 0; r < 8; ++r) rsum[r] = 0.f;
    #pragma unroll
    for (int i = 0; i < 16; ++i) {
        float4 v = plane[i * 256 + t];
        rsum[i >> 1] += v.x + v.y + v.z + v.w;
    }
    __shared__ float part[8][256];
    #pragma unroll
    for (int r = 0; r < 8; ++r) part[r][t] = rsum[r];
    __syncthreads();
    int R  = t >> 5;
    int cw = t & 31;
    float s = 0.f;
    #pragma unroll
    for (int a = 0; a < 8; ++a) s += part[R][a * 32 + cw];
    s += __shfl_xor(s, 1);
    s += __shfl_xor(s, 2);
    if ((t & 3) == 0) {
        int shot = b >> 8, c = b & 255;
        int p = shot * 64 + R * 8 + (cw >> 2);
        praw[(size_t)p * NCH + c] = s * (1.0f / 256.0f);
    }
}

// ---------------------------------------------------------------------------
// Kernel 1b: per-proto center + safe-normalize; emit fp16 hi/lo split of the
// NORMALIZED proto in B-fragment layout PTh[((k>>3)*320 + p)*8 + (k&7)].
// ---------------------------------------------------------------------------
__device__ __forceinline__ float block_sum256(float x, float* ws4, int t) {
    #pragma unroll
    for (int o = 1; o < 64; o <<= 1) x += __shfl_xor(x, o);
    if ((t & 63) == 0) ws4[t >> 6] = x;
    __syncthreads();
    float r = ws4[0] + ws4[1] + ws4[2] + ws4[3];
    __syncthreads();
    return r;
}

__global__ __launch_bounds__(256) void k_norm(const float* __restrict__ praw,
                                              _Float16* __restrict__ PTh,
                                              _Float16* __restrict__ PTl,
                                              float* __restrict__ sp) {
    int p = blockIdx.x;
    int c = threadIdx.x;
    __shared__ float ws4[4];
    float v = praw[p * NCH + c];
    float mean = block_sum256(v, ws4, c) * (1.0f / 256.0f);
    float cen = v - mean;
    float n2 = block_sum256(cen * cen, ws4, c);
    float inv = 1.0f / fmaxf(sqrtf(n2), EPSN);
    float pn = cen * inv;
    _Float16 hi = (_Float16)pn;
    float lo = (pn - (float)hi) * 2048.0f;
    size_t idx = ((size_t)(c >> 3) * NPROT + p) * 8 + (c & 7);
    PTh[idx] = hi;
    PTl[idx] = (_Float16)lo;
    float ssum = block_sum256(pn, ws4, c);
    if (c == 0) sp[p] = ssum;
}

// ---------------------------------------------------------------------------
// Kernel 2: MFMA GEMM (16 px x 320 protos x K=256) + softmax epilogue.
// (byte-identical to R5)
// ---------------------------------------------------------------------------
__global__ __launch_bounds__(256, 4) void k_main(const float* __restrict__ qry,
                                                 const _Float16* __restrict__ PTh,
                                                 const _Float16* __restrict__ PTl,
                                                 float* __restrict__ out) {
    __shared__ __align__(16) _Float16 Ah[16 * 256];    // 8 KB, swizzled
    __shared__ __align__(16) _Float16 Al[16 * 256];    // 8 KB, swizzled
    __shared__ __align__(16) float red1[64 * 16];      // [c0][px] partial sums
    __shared__ __align__(16) float red2[64 * 16];      // [c0][px] partial sumsq
    __shared__ float meanv[16], invnv[16];
    __shared__ float Mw[4][16], Sw[4][16], Tw[4][16], Iw[4][16];
    int t = threadIdx.x;
    // XCD-chunked bijective swizzle (1024 % 8 == 0)
    int bid = blockIdx.x;
    int tile = (bid & 7) * 128 + (bid >> 3);
    int pixbase = tile * 16;

    // ---- stage: 4 float4 loads -> 16 q-values in REGISTERS + px partials ----
    int f4 = t & 3;                // which float4-of-pixels (0..3)
    int c0 = t >> 2;               // 0..63
    float qv[4][4];                // [i][j]: channel c0+64i, pixel f4*4+j
    {
        float ps1[4] = {0.f, 0.f, 0.f, 0.f};
        float ps2[4] = {0.f, 0.f, 0.f, 0.f};
        #pragma unroll
        for (int i = 0; i < 4; ++i) {
            int c = c0 + 64 * i;
            float4 v = *(const float4*)(qry + (size_t)c * HW + pixbase + f4 * 4);
            qv[i][0] = v.x; qv[i][1] = v.y; qv[i][2] = v.z; qv[i][3] = v.w;
            ps1[0] += v.x; ps2[0] = fmaf(v.x, v.x, ps2[0]);
            ps1[1] += v.y; ps2[1] = fmaf(v.y, v.y, ps2[1]);
            ps1[2] += v.z; ps2[2] = fmaf(v.z, v.z, ps2[2]);
            ps1[3] += v.w; ps2[3] = fmaf(v.w, v.w, ps2[3]);
        }
        *(float4*)&red1[c0 * 16 + f4 * 4] = *(float4*)ps1;
        *(float4*)&red2[c0 * 16 + f4 * 4] = *(float4*)ps2;
    }
    __syncthreads();
    if (t < 16) {
        float s1 = 0.f, s2 = 0.f;
        #pragma unroll
        for (int j = 0; j < 64; ++j) { s1 += red1[j * 16 + t]; s2 += red2[j * 16 + t]; }
        float mean = s1 * (1.0f / 256.0f);
        float n2 = fmaxf(s2 - s1 * mean, 0.f);   // sum (q-mean)^2
        meanv[t] = mean;
        invnv[t] = 1.0f / fmaxf(sqrtf(n2), EPSN);
    }
    __syncthreads();

    // ---- normalize in-register, fp16 hi/lo split -> swizzled LDS A-tiles ----
    {
        char* AhB = (char*)Ah;
        char* AlB = (char*)Al;
        #pragma unroll
        for (int j = 0; j < 4; ++j) {
            int px = f4 * 4 + j;
            float mean = meanv[px], invn = invnv[px];
            #pragma unroll
            for (int i = 0; i < 4; ++i) {
                int c = c0 + 64 * i;
                float qn = (qv[i][j] - mean) * invn;
                _Float16 h = (_Float16)qn;
                _Float16 l = (_Float16)((qn - (float)h) * 2048.0f);
                int off = px * 512 + ((2 * c) ^ ((px & 7) << 4));
                *(_Float16*)(AhB + off) = h;
                *(_Float16*)(AlB + off) = l;
            }
        }
    }
    __syncthreads();

    // ---- MFMA main loop: wave w owns protos [w*80, w*80+80); nt outer ----
    int lane = t & 63, w = t >> 6;
    int col = lane & 15, g4 = lane >> 4;
    int aswz = (col & 7) << 4;
    const char* AhB = (const char*)Ah + col * 512;
    const char* AlB = (const char*)Al + col * 512;
    const half8* BH = (const half8*)PTh;
    const half8* BL = (const half8*)PTl;

    f32x4 dva[5];

    #pragma unroll
    for (int nt = 0; nt < 5; ++nt) {
        int nb = w * 80 + nt * 16 + col;
        f32x4 a1 = {0.f, 0.f, 0.f, 0.f};
        f32x4 a2 = {0.f, 0.f, 0.f, 0.f};
        #pragma unroll
        for (int kb = 0; kb < 8; ++kb) {
            half8 bh = BH[(kb * 4 + g4) * 320 + nb];
            half8 bl = BL[(kb * 4 + g4) * 320 + nb];
            int koff = (kb * 64 + g4 * 16) ^ aswz;
            half8 ah = *(const half8*)(AhB + koff);
            half8 al = *(const half8*)(AlB + koff);
            a1 = __builtin_amdgcn_mfma_f32_16x16x32_f16(ah, bh, a1, 0, 0, 0);
            a2 = __builtin_amdgcn_mfma_f32_16x16x32_f16(ah, bl, a2, 0, 0, 0);
            a2 = __builtin_amdgcn_mfma_f32_16x16x32_f16(al, bh, a2, 0, 0, 0);
        }
        dva[nt] = a1 + a2 * (1.0f / 2048.0f);
    }

    // ---- softmax partials per pixel over this wave's 80 protos ----
    #pragma unroll
    for (int r = 0; r < 4; ++r) {
        int pixel = g4 * 4 + r;          // D layout: row = (lane>>4)*4 + reg
        float dv[5];
        #pragma unroll
        for (int nt = 0; nt < 5; ++nt) dv[nt] = TAU * dva[nt][r];
        float gm = dv[0];
        float gi = (float)(w * 80 + col);
        #pragma unroll
        for (int nt = 1; nt < 5; ++nt)
            if (dv[nt] > gm) { gm = dv[nt]; gi = (float)(w * 80 + nt * 16 + col); }
        // reduce (max, argmax) over the 16 fragment columns
        #pragma unroll
        for (int o = 1; o < 16; o <<= 1) {
            float om = __shfl_xor(gm, o);
            float oi = __shfl_xor(gi, o);
            if (om > gm || (om == gm && oi < gi)) { gm = om; gi = oi; }
        }
        float S = 0.f, T = 0.f;
        #pragma unroll
        for (int nt = 0; nt < 5; ++nt) {
            float e = __expf(dv[nt] - gm);
            S += e;
            T = fmaf(e, dv[nt], T);
        }
        #pragma unroll
        for (int o = 1; o < 16; o <<= 1) { S += __shfl_xor(S, o); T += __shfl_xor(T, o); }
        if (col == 0) { Mw[w][pixel] = gm; Sw[w][pixel] = S; Tw[w][pixel] = T; Iw[w][pixel] = gi; }
    }
    __syncthreads();

    // ---- merge 4 waves (disjoint ascending proto ranges), write out ----
    if (t < 16) {
        float gm = Mw[0][t], gi = Iw[0][t];
        #pragma unroll
        for (int k = 1; k < 4; ++k)
            if (Mw[k][t] > gm) { gm = Mw[k][t]; gi = Iw[k][t]; }
        float S = 0.f, T = 0.f;
        #pragma unroll
        for (int k = 0; k < 4; ++k) {
            float sc = __expf(Mw[k][t] - gm);
            S = fmaf(Sw[k][t], sc, S);
            T = fmaf(Tw[k][t], sc, T);
        }
        out[pixbase + t] = T / S;           // pred_grid
        out[HW + pixbase + t] = gi;         // debug_assign
    }
}

extern "C" void kernel_launch(void* const* d_in, const int* in_sizes, int n_in,
                              void* d_out, int out_size, void* d_ws, size_t ws_size,
                              hipStream_t stream) {
    const float* qry   = (const float*)d_in[0];   // (1,1,256,128,128)
    const float* sup_x = (const float*)d_in[1];   // (1,5,1,256,128,128)
    float* out = (float*)d_out;                   // 16384 pred + 16384 assign

    float* praw   = (float*)d_ws;                        // 320*256 fp32
    _Float16* PTh = (_Float16*)(praw + NPROT * NCH);     // 320*256 fp16 (frag layout)
    _Float16* PTl = PTh + NPROT * NCH;                   // 320*256 fp16 (frag layout)
    float* sp     = (float*)(PTl + NPROT * NCH);         // 320 fp32

    k_pool<<<5 * 256, 256, 0, stream>>>(sup_x, praw);
    k_norm<<<NPROT, 256, 0, stream>>>(praw, PTh, PTl, sp);
    // PROBE: k_main x3 (idempotent). dur_R6 - dur_R5 = 2 * k_main_warm.
    k_main<<<HW / 16, 256, 0, stream>>>(qry, PTh, PTl, out);
    k_main<<<HW / 16, 256, 0, stream>>>(qry, PTh, PTl, out);
    k_main<<<HW / 16, 256, 0, stream>>>(qry, PTh, PTl, out);
}

// Round 7
// 158.346 us; speedup vs baseline: 1.2337x; 1.2337x over previous
//
#include <hip/hip_runtime.h>

#define NCH   256
#define NPROT 320
#define HW    16384      // 128*128
#define TAU   20.0f
#define EPSN  1e-4f

typedef _Float16 half8 __attribute__((ext_vector_type(8)));
typedef float    f32x4 __attribute__((ext_vector_type(4)));

// ---------------------------------------------------------------------------
// Kernel 1a: avg-pool sup_x (5,256,128,128) over 16x16 cells -> praw[p][c]
// (unchanged; HBM-bound at ~13us: must read 84 MB)
// ---------------------------------------------------------------------------
__global__ __launch_bounds__(256) void k_pool(const float* __restrict__ sup_x,
                                              float* __restrict__ praw) {
    int b = blockIdx.x;            // s*256 + c
    int t = threadIdx.x;
    const float4* plane = (const float4*)(sup_x + (size_t)b * HW);
    float rsum[8];
    #pragma unroll
    for (int r = 0; r < 8; ++r) rsum[r] = 0.f;
    #pragma unroll
    for (int i = 0; i < 16; ++i) {
        float4 v = plane[i * 256 + t];
        rsum[i >> 1] += v.x + v.y + v.z + v.w;
    }
    __shared__ float part[8][256];
    #pragma unroll
    for (int r = 0; r < 8; ++r) part[r][t] = rsum[r];
    __syncthreads();
    int R  = t >> 5;
    int cw = t & 31;
    float s = 0.f;
    #pragma unroll
    for (int a = 0; a < 8; ++a) s += part[R][a * 32 + cw];
    s += __shfl_xor(s, 1);
    s += __shfl_xor(s, 2);
    if ((t & 3) == 0) {
        int shot = b >> 8, c = b & 255;
        int p = shot * 64 + R * 8 + (cw >> 2);
        praw[(size_t)p * NCH + c] = s * (1.0f / 256.0f);
    }
}

// ---------------------------------------------------------------------------
// Kernel 1b: per-proto center + safe-normalize; emit fp16 hi/lo split of the
// NORMALIZED proto in B-fragment layout PTh[((k>>3)*320 + p)*8 + (k&7)].
// ---------------------------------------------------------------------------
__device__ __forceinline__ float block_sum256(float x, float* ws4, int t) {
    #pragma unroll
    for (int o = 1; o < 64; o <<= 1) x += __shfl_xor(x, o);
    if ((t & 63) == 0) ws4[t >> 6] = x;
    __syncthreads();
    float r = ws4[0] + ws4[1] + ws4[2] + ws4[3];
    __syncthreads();
    return r;
}

__global__ __launch_bounds__(256) void k_norm(const float* __restrict__ praw,
                                              _Float16* __restrict__ PTh,
                                              _Float16* __restrict__ PTl,
                                              float* __restrict__ sp) {
    int p = blockIdx.x;
    int c = threadIdx.x;
    __shared__ float ws4[4];
    float v = praw[p * NCH + c];
    float mean = block_sum256(v, ws4, c) * (1.0f / 256.0f);
    float cen = v - mean;
    float n2 = block_sum256(cen * cen, ws4, c);
    float inv = 1.0f / fmaxf(sqrtf(n2), EPSN);
    float pn = cen * inv;
    _Float16 hi = (_Float16)pn;
    float lo = (pn - (float)hi) * 2048.0f;
    size_t idx = ((size_t)(c >> 3) * NPROT + p) * 8 + (c & 7);
    PTh[idx] = hi;
    PTl[idx] = (_Float16)lo;
    float ssum = block_sum256(pn, ws4, c);
    if (c == 0) sp[p] = ssum;
}

// ---------------------------------------------------------------------------
// Kernel 2: MFMA GEMM (16 px x 320 protos x K=256) + softmax epilogue.
// R7 change (single variable vs R5): explicit depth-2 B-prefetch in a flat
// 40-step fully-unrolled loop. R6 probe measured k_main_warm ~= 18us; the
// un-prefetched dependent chain global_load->mfma exposes ~220cy L2 latency
// x 40 steps. This is the unexplored cell {prefetch x 4 blocks/CU} of the
// 2x2 whose other three cells all measured 18-20us.
// ---------------------------------------------------------------------------
__global__ __launch_bounds__(256, 4) void k_main(const float* __restrict__ qry,
                                                 const _Float16* __restrict__ PTh,
                                                 const _Float16* __restrict__ PTl,
                                                 float* __restrict__ out) {
    __shared__ __align__(16) _Float16 Ah[16 * 256];    // 8 KB, swizzled
    __shared__ __align__(16) _Float16 Al[16 * 256];    // 8 KB, swizzled
    __shared__ __align__(16) float red1[64 * 16];      // [c0][px] partial sums
    __shared__ __align__(16) float red2[64 * 16];      // [c0][px] partial sumsq
    __shared__ float meanv[16], invnv[16];
    __shared__ float Mw[4][16], Sw[4][16], Tw[4][16], Iw[4][16];
    int t = threadIdx.x;
    // XCD-chunked bijective swizzle (1024 % 8 == 0)
    int bid = blockIdx.x;
    int tile = (bid & 7) * 128 + (bid >> 3);
    int pixbase = tile * 16;

    // ---- stage: 4 float4 loads -> 16 q-values in REGISTERS + px partials ----
    int f4 = t & 3;                // which float4-of-pixels (0..3)
    int c0 = t >> 2;               // 0..63
    float qv[4][4];                // [i][j]: channel c0+64i, pixel f4*4+j
    {
        float ps1[4] = {0.f, 0.f, 0.f, 0.f};
        float ps2[4] = {0.f, 0.f, 0.f, 0.f};
        #pragma unroll
        for (int i = 0; i < 4; ++i) {
            int c = c0 + 64 * i;
            float4 v = *(const float4*)(qry + (size_t)c * HW + pixbase + f4 * 4);
            qv[i][0] = v.x; qv[i][1] = v.y; qv[i][2] = v.z; qv[i][3] = v.w;
            ps1[0] += v.x; ps2[0] = fmaf(v.x, v.x, ps2[0]);
            ps1[1] += v.y; ps2[1] = fmaf(v.y, v.y, ps2[1]);
            ps1[2] += v.z; ps2[2] = fmaf(v.z, v.z, ps2[2]);
            ps1[3] += v.w; ps2[3] = fmaf(v.w, v.w, ps2[3]);
        }
        *(float4*)&red1[c0 * 16 + f4 * 4] = *(float4*)ps1;
        *(float4*)&red2[c0 * 16 + f4 * 4] = *(float4*)ps2;
    }
    __syncthreads();
    if (t < 16) {
        float s1 = 0.f, s2 = 0.f;
        #pragma unroll
        for (int j = 0; j < 64; ++j) { s1 += red1[j * 16 + t]; s2 += red2[j * 16 + t]; }
        float mean = s1 * (1.0f / 256.0f);
        float n2 = fmaxf(s2 - s1 * mean, 0.f);   // sum (q-mean)^2
        meanv[t] = mean;
        invnv[t] = 1.0f / fmaxf(sqrtf(n2), EPSN);
    }
    __syncthreads();

    // ---- normalize in-register, fp16 hi/lo split -> swizzled LDS A-tiles ----
    {
        char* AhB = (char*)Ah;
        char* AlB = (char*)Al;
        #pragma unroll
        for (int j = 0; j < 4; ++j) {
            int px = f4 * 4 + j;
            float mean = meanv[px], invn = invnv[px];
            #pragma unroll
            for (int i = 0; i < 4; ++i) {
                int c = c0 + 64 * i;
                float qn = (qv[i][j] - mean) * invn;
                _Float16 h = (_Float16)qn;
                _Float16 l = (_Float16)((qn - (float)h) * 2048.0f);
                int off = px * 512 + ((2 * c) ^ ((px & 7) << 4));
                *(_Float16*)(AhB + off) = h;
                *(_Float16*)(AlB + off) = l;
            }
        }
    }
    __syncthreads();

    // ---- MFMA main loop: wave w owns protos [w*80, w*80+80) ----
    // Flat 40-step (nt*8+kb) fully-unrolled loop, depth-2 B prefetch rotation.
    int lane = t & 63, w = t >> 6;
    int col = lane & 15, g4 = lane >> 4;
    int aswz = (col & 7) << 4;
    const char* AhB = (const char*)Ah + col * 512;
    const char* AlB = (const char*)Al + col * 512;
    const half8* BH = (const half8*)PTh;
    const half8* BL = (const half8*)PTl;
    int nb0 = w * 80 + col;

    f32x4 dva[5];
    {
        half8 pbh[2], pbl[2];
        // preload steps 0 (nt0,kb0) and 1 (nt0,kb1)
        pbh[0] = BH[(0 * 4 + g4) * 320 + nb0];
        pbl[0] = BL[(0 * 4 + g4) * 320 + nb0];
        pbh[1] = BH[(1 * 4 + g4) * 320 + nb0];
        pbl[1] = BL[(1 * 4 + g4) * 320 + nb0];
        f32x4 a1 = {0.f, 0.f, 0.f, 0.f};
        f32x4 a2 = {0.f, 0.f, 0.f, 0.f};
        #pragma unroll
        for (int s = 0; s < 40; ++s) {
            int nt = s >> 3, kb = s & 7;
            int buf = s & 1;
            half8 bh = pbh[buf], bl = pbl[buf];
            if (s + 2 < 40) {   // static (full unroll): issue step s+2 loads
                int nt2 = (s + 2) >> 3, kb2 = (s + 2) & 7;
                int idx2 = (kb2 * 4 + g4) * 320 + nb0 + nt2 * 16;
                pbh[buf] = BH[idx2];
                pbl[buf] = BL[idx2];
            }
            int koff = (kb * 64 + g4 * 16) ^ aswz;
            half8 ah = *(const half8*)(AhB + koff);
            half8 al = *(const half8*)(AlB + koff);
            a1 = __builtin_amdgcn_mfma_f32_16x16x32_f16(ah, bh, a1, 0, 0, 0);
            a2 = __builtin_amdgcn_mfma_f32_16x16x32_f16(ah, bl, a2, 0, 0, 0);
            a2 = __builtin_amdgcn_mfma_f32_16x16x32_f16(al, bh, a2, 0, 0, 0);
            if (kb == 7) {
                dva[nt] = a1 + a2 * (1.0f / 2048.0f);
                a1 = (f32x4){0.f, 0.f, 0.f, 0.f};
                a2 = (f32x4){0.f, 0.f, 0.f, 0.f};
            }
        }
    }

    // ---- softmax partials per pixel over this wave's 80 protos ----
    #pragma unroll
    for (int r = 0; r < 4; ++r) {
        int pixel = g4 * 4 + r;          // D layout: row = (lane>>4)*4 + reg
        float dv[5];
        #pragma unroll
        for (int nt = 0; nt < 5; ++nt) dv[nt] = TAU * dva[nt][r];
        float gm = dv[0];
        float gi = (float)(w * 80 + col);
        #pragma unroll
        for (int nt = 1; nt < 5; ++nt)
            if (dv[nt] > gm) { gm = dv[nt]; gi = (float)(w * 80 + nt * 16 + col); }
        // reduce (max, argmax) over the 16 fragment columns
        #pragma unroll
        for (int o = 1; o < 16; o <<= 1) {
            float om = __shfl_xor(gm, o);
            float oi = __shfl_xor(gi, o);
            if (om > gm || (om == gm && oi < gi)) { gm = om; gi = oi; }
        }
        float S = 0.f, T = 0.f;
        #pragma unroll
        for (int nt = 0; nt < 5; ++nt) {
            float e = __expf(dv[nt] - gm);
            S += e;
            T = fmaf(e, dv[nt], T);
        }
        #pragma unroll
        for (int o = 1; o < 16; o <<= 1) { S += __shfl_xor(S, o); T += __shfl_xor(T, o); }
        if (col == 0) { Mw[w][pixel] = gm; Sw[w][pixel] = S; Tw[w][pixel] = T; Iw[w][pixel] = gi; }
    }
    __syncthreads();

    // ---- merge 4 waves (disjoint ascending proto ranges), write out ----
    if (t < 16) {
        float gm = Mw[0][t], gi = Iw[0][t];
        #pragma unroll
        for (int k = 1; k < 4; ++k)
            if (Mw[k][t] > gm) { gm = Mw[k][t]; gi = Iw[k][t]; }
        float S = 0.f, T = 0.f;
        #pragma unroll
        for (int k = 0; k < 4; ++k) {
            float sc = __expf(Mw[k][t] - gm);
            S = fmaf(Sw[k][t], sc, S);
            T = fmaf(Tw[k][t], sc, T);
        }
        out[pixbase + t] = T / S;           // pred_grid
        out[HW + pixbase + t] = gi;         // debug_assign
    }
}

extern "C" void kernel_launch(void* const* d_in, const int* in_sizes, int n_in,
                              void* d_out, int out_size, void* d_ws, size_t ws_size,
                              hipStream_t stream) {
    const float* qry   = (const float*)d_in[0];   // (1,1,256,128,128)
    const float* sup_x = (const float*)d_in[1];   // (1,5,1,256,128,128)
    float* out = (float*)d_out;                   // 16384 pred + 16384 assign

    float* praw   = (float*)d_ws;                        // 320*256 fp32
    _Float16* PTh = (_Float16*)(praw + NPROT * NCH);     // 320*256 fp16 (frag layout)
    _Float16* PTl = PTh + NPROT * NCH;                   // 320*256 fp16 (frag layout)
    float* sp     = (float*)(PTl + NPROT * NCH);         // 320 fp32

    k_pool<<<5 * 256, 256, 0, stream>>>(sup_x, praw);
    k_norm<<<NPROT, 256, 0, stream>>>(praw, PTh, PTl, sp);
    k_main<<<HW / 16, 256, 0, stream>>>(qry, PTh, PTl, out);
}

// Round 8
// 156.871 us; speedup vs baseline: 1.2453x; 1.0094x over previous
//
#include <hip/hip_runtime.h>

#define NCH   256
#define NPROT 320
#define HW    16384      // 128*128
#define TAU   20.0f
#define EPSN  1e-4f

typedef _Float16 half8 __attribute__((ext_vector_type(8)));
typedef float    f32x4 __attribute__((ext_vector_type(4)));

// ---------------------------------------------------------------------------
// Kernel 1a: avg-pool sup_x (5,256,128,128) over 16x16 cells -> praw[p][c]
// (unchanged; HBM-bound at ~13us: must read 84 MB)
// ---------------------------------------------------------------------------
__global__ __launch_bounds__(256) void k_pool(const float* __restrict__ sup_x,
                                              float* __restrict__ praw) {
    int b = blockIdx.x;            // s*256 + c
    int t = threadIdx.x;
    const float4* plane = (const float4*)(sup_x + (size_t)b * HW);
    float rsum[8];
    #pragma unroll
    for (int r = 0; r < 8; ++r) rsum[r] = 0.f;
    #pragma unroll
    for (int i = 0; i < 16; ++i) {
        float4 v = plane[i * 256 + t];
        rsum[i >> 1] += v.x + v.y + v.z + v.w;
    }
    __shared__ float part[8][256];
    #pragma unroll
    for (int r = 0; r < 8; ++r) part[r][t] = rsum[r];
    __syncthreads();
    int R  = t >> 5;
    int cw = t & 31;
    float s = 0.f;
    #pragma unroll
    for (int a = 0; a < 8; ++a) s += part[R][a * 32 + cw];
    s += __shfl_xor(s, 1);
    s += __shfl_xor(s, 2);
    if ((t & 3) == 0) {
        int shot = b >> 8, c = b & 255;
        int p = shot * 64 + R * 8 + (cw >> 2);
        praw[(size_t)p * NCH + c] = s * (1.0f / 256.0f);
    }
}

// ---------------------------------------------------------------------------
// Kernel 1b: per-proto center + safe-normalize; emit fp16 hi/lo split of the
// NORMALIZED proto in B-fragment layout PTh[((k>>3)*320 + p)*8 + (k&7)].
// ---------------------------------------------------------------------------
__device__ __forceinline__ float block_sum256(float x, float* ws4, int t) {
    #pragma unroll
    for (int o = 1; o < 64; o <<= 1) x += __shfl_xor(x, o);
    if ((t & 63) == 0) ws4[t >> 6] = x;
    __syncthreads();
    float r = ws4[0] + ws4[1] + ws4[2] + ws4[3];
    __syncthreads();
    return r;
}

__global__ __launch_bounds__(256) void k_norm(const float* __restrict__ praw,
                                              _Float16* __restrict__ PTh,
                                              _Float16* __restrict__ PTl,
                                              float* __restrict__ sp) {
    int p = blockIdx.x;
    int c = threadIdx.x;
    __shared__ float ws4[4];
    float v = praw[p * NCH + c];
    float mean = block_sum256(v, ws4, c) * (1.0f / 256.0f);
    float cen = v - mean;
    float n2 = block_sum256(cen * cen, ws4, c);
    float inv = 1.0f / fmaxf(sqrtf(n2), EPSN);
    float pn = cen * inv;
    _Float16 hi = (_Float16)pn;
    float lo = (pn - (float)hi) * 2048.0f;
    size_t idx = ((size_t)(c >> 3) * NPROT + p) * 8 + (c & 7);
    PTh[idx] = hi;
    PTl[idx] = (_Float16)lo;
    float ssum = block_sum256(pn, ws4, c);
    if (c == 0) sp[p] = ssum;
}

// ---------------------------------------------------------------------------
// Kernel 2: MFMA GEMM (16 px x 320 protos x K=256) + softmax epilogue.
// R8 change (single variable vs R7): B-prefetch distance 2 -> 6.
// Post-mortem R7: each unrolled step is ~30cy of issue; distance-2 covers
// ~60cy vs ~200cy L2 latency -> pipeline was 4x too shallow. Distance-6
// covers ~180cy. Six-slot rotation, statically indexed (full 40-step unroll).
// VGPR ~110 < 128 cap of launch_bounds(256,4): no spill, occupancy kept.
// ---------------------------------------------------------------------------
__global__ __launch_bounds__(256, 4) void k_main(const float* __restrict__ qry,
                                                 const _Float16* __restrict__ PTh,
                                                 const _Float16* __restrict__ PTl,
                                                 float* __restrict__ out) {
    __shared__ __align__(16) _Float16 Ah[16 * 256];    // 8 KB, swizzled
    __shared__ __align__(16) _Float16 Al[16 * 256];    // 8 KB, swizzled
    __shared__ __align__(16) float red1[64 * 16];      // [c0][px] partial sums
    __shared__ __align__(16) float red2[64 * 16];      // [c0][px] partial sumsq
    __shared__ float meanv[16], invnv[16];
    __shared__ float Mw[4][16], Sw[4][16], Tw[4][16], Iw[4][16];
    int t = threadIdx.x;
    // XCD-chunked bijective swizzle (1024 % 8 == 0)
    int bid = blockIdx.x;
    int tile = (bid & 7) * 128 + (bid >> 3);
    int pixbase = tile * 16;

    // ---- stage: 4 float4 loads -> 16 q-values in REGISTERS + px partials ----
    int f4 = t & 3;                // which float4-of-pixels (0..3)
    int c0 = t >> 2;               // 0..63
    float qv[4][4];                // [i][j]: channel c0+64i, pixel f4*4+j
    {
        float ps1[4] = {0.f, 0.f, 0.f, 0.f};
        float ps2[4] = {0.f, 0.f, 0.f, 0.f};
        #pragma unroll
        for (int i = 0; i < 4; ++i) {
            int c = c0 + 64 * i;
            float4 v = *(const float4*)(qry + (size_t)c * HW + pixbase + f4 * 4);
            qv[i][0] = v.x; qv[i][1] = v.y; qv[i][2] = v.z; qv[i][3] = v.w;
            ps1[0] += v.x; ps2[0] = fmaf(v.x, v.x, ps2[0]);
            ps1[1] += v.y; ps2[1] = fmaf(v.y, v.y, ps2[1]);
            ps1[2] += v.z; ps2[2] = fmaf(v.z, v.z, ps2[2]);
            ps1[3] += v.w; ps2[3] = fmaf(v.w, v.w, ps2[3]);
        }
        *(float4*)&red1[c0 * 16 + f4 * 4] = *(float4*)ps1;
        *(float4*)&red2[c0 * 16 + f4 * 4] = *(float4*)ps2;
    }
    __syncthreads();
    if (t < 16) {
        float s1 = 0.f, s2 = 0.f;
        #pragma unroll
        for (int j = 0; j < 64; ++j) { s1 += red1[j * 16 + t]; s2 += red2[j * 16 + t]; }
        float mean = s1 * (1.0f / 256.0f);
        float n2 = fmaxf(s2 - s1 * mean, 0.f);   // sum (q-mean)^2
        meanv[t] = mean;
        invnv[t] = 1.0f / fmaxf(sqrtf(n2), EPSN);
    }
    __syncthreads();

    // ---- normalize in-register, fp16 hi/lo split -> swizzled LDS A-tiles ----
    {
        char* AhB = (char*)Ah;
        char* AlB = (char*)Al;
        #pragma unroll
        for (int j = 0; j < 4; ++j) {
            int px = f4 * 4 + j;
            float mean = meanv[px], invn = invnv[px];
            #pragma unroll
            for (int i = 0; i < 4; ++i) {
                int c = c0 + 64 * i;
                float qn = (qv[i][j] - mean) * invn;
                _Float16 h = (_Float16)qn;
                _Float16 l = (_Float16)((qn - (float)h) * 2048.0f);
                int off = px * 512 + ((2 * c) ^ ((px & 7) << 4));
                *(_Float16*)(AhB + off) = h;
                *(_Float16*)(AlB + off) = l;
            }
        }
    }
    __syncthreads();

    // ---- MFMA main loop: wave w owns protos [w*80, w*80+80) ----
    // Flat 40-step (nt*8+kb) fully-unrolled loop, DEPTH-6 B prefetch rotation.
    int lane = t & 63, w = t >> 6;
    int col = lane & 15, g4 = lane >> 4;
    int aswz = (col & 7) << 4;
    const char* AhB = (const char*)Ah + col * 512;
    const char* AlB = (const char*)Al + col * 512;
    const half8* BH = (const half8*)PTh;
    const half8* BL = (const half8*)PTl;
    int nb0 = w * 80 + col;

    f32x4 dva[5];
    {
        half8 pbh[6], pbl[6];
        // preload steps 0..5  (step s: nt=s>>3, kb=s&7)
        #pragma unroll
        for (int s = 0; s < 6; ++s) {
            int nt = s >> 3, kb = s & 7;
            int idx = (kb * 4 + g4) * 320 + nb0 + nt * 16;
            pbh[s] = BH[idx];
            pbl[s] = BL[idx];
        }
        f32x4 a1 = {0.f, 0.f, 0.f, 0.f};
        f32x4 a2 = {0.f, 0.f, 0.f, 0.f};
        #pragma unroll
        for (int s = 0; s < 40; ++s) {
            int nt = s >> 3, kb = s & 7;
            int buf = s % 6;                 // static after full unroll
            half8 bh = pbh[buf], bl = pbl[buf];
            if (s + 6 < 40) {                // issue step s+6 loads into freed slot
                int nt6 = (s + 6) >> 3, kb6 = (s + 6) & 7;
                int idx6 = (kb6 * 4 + g4) * 320 + nb0 + nt6 * 16;
                pbh[buf] = BH[idx6];
                pbl[buf] = BL[idx6];
            }
            int koff = (kb * 64 + g4 * 16) ^ aswz;
            half8 ah = *(const half8*)(AhB + koff);
            half8 al = *(const half8*)(AlB + koff);
            a1 = __builtin_amdgcn_mfma_f32_16x16x32_f16(ah, bh, a1, 0, 0, 0);
            a2 = __builtin_amdgcn_mfma_f32_16x16x32_f16(ah, bl, a2, 0, 0, 0);
            a2 = __builtin_amdgcn_mfma_f32_16x16x32_f16(al, bh, a2, 0, 0, 0);
            if (kb == 7) {
                dva[nt] = a1 + a2 * (1.0f / 2048.0f);
                a1 = (f32x4){0.f, 0.f, 0.f, 0.f};
                a2 = (f32x4){0.f, 0.f, 0.f, 0.f};
            }
        }
    }

    // ---- softmax partials per pixel over this wave's 80 protos ----
    #pragma unroll
    for (int r = 0; r < 4; ++r) {
        int pixel = g4 * 4 + r;          // D layout: row = (lane>>4)*4 + reg
        float dv[5];
        #pragma unroll
        for (int nt = 0; nt < 5; ++nt) dv[nt] = TAU * dva[nt][r];
        float gm = dv[0];
        float gi = (float)(w * 80 + col);
        #pragma unroll
        for (int nt = 1; nt < 5; ++nt)
            if (dv[nt] > gm) { gm = dv[nt]; gi = (float)(w * 80 + nt * 16 + col); }
        // reduce (max, argmax) over the 16 fragment columns
        #pragma unroll
        for (int o = 1; o < 16; o <<= 1) {
            float om = __shfl_xor(gm, o);
            float oi = __shfl_xor(gi, o);
            if (om > gm || (om == gm && oi < gi)) { gm = om; gi = oi; }
        }
        float S = 0.f, T = 0.f;
        #pragma unroll
        for (int nt = 0; nt < 5; ++nt) {
            float e = __expf(dv[nt] - gm);
            S += e;
            T = fmaf(e, dv[nt], T);
        }
        #pragma unroll
        for (int o = 1; o < 16; o <<= 1) { S += __shfl_xor(S, o); T += __shfl_xor(T, o); }
        if (col == 0) { Mw[w][pixel] = gm; Sw[w][pixel] = S; Tw[w][pixel] = T; Iw[w][pixel] = gi; }
    }
    __syncthreads();

    // ---- merge 4 waves (disjoint ascending proto ranges), write out ----
    if (t < 16) {
        float gm = Mw[0][t], gi = Iw[0][t];
        #pragma unroll
        for (int k = 1; k < 4; ++k)
            if (Mw[k][t] > gm) { gm = Mw[k][t]; gi = Iw[k][t]; }
        float S = 0.f, T = 0.f;
        #pragma unroll
        for (int k = 0; k < 4; ++k) {
            float sc = __expf(Mw[k][t] - gm);
            S = fmaf(Sw[k][t], sc, S);
            T = fmaf(Tw[k][t], sc, T);
        }
        out[pixbase + t] = T / S;           // pred_grid
        out[HW + pixbase + t] = gi;         // debug_assign
    }
}

extern "C" void kernel_launch(void* const* d_in, const int* in_sizes, int n_in,
                              void* d_out, int out_size, void* d_ws, size_t ws_size,
                              hipStream_t stream) {
    const float* qry   = (const float*)d_in[0];   // (1,1,256,128,128)
    const float* sup_x = (const float*)d_in[1];   // (1,5,1,256,128,128)
    float* out = (float*)d_out;                   // 16384 pred + 16384 assign

    float* praw   = (float*)d_ws;                        // 320*256 fp32
    _Float16* PTh = (_Float16*)(praw + NPROT * NCH);     // 320*256 fp16 (frag layout)
    _Float16* PTl = PTh + NPROT * NCH;                   // 320*256 fp16 (frag layout)
    float* sp     = (float*)(PTl + NPROT * NCH);         // 320 fp32

    k_pool<<<5 * 256, 256, 0, stream>>>(sup_x, praw);
    k_norm<<<NPROT, 256, 0, stream>>>(praw, PTh, PTl, sp);
    k_main<<<HW / 16, 256, 0, stream>>>(qry, PTh, PTl, out);
}